// Round 3
// baseline (22539.671 us; speedup 1.0000x reference)
//
#include <hip/hip_runtime.h>
#include <stdint.h>

#define T_STEPS 1024
#define BATCH 64
#define HID 512
#define NGROUP 64               // workgroups per layer
#define NLAYER 3
#define NWG (NGROUP * NLAYER)   // 192
#define THREADS 256
#define S_TOTAL (T_STEPS + NLAYER - 1)  // 1026 global steps
#define HSLICE (BATCH * HID)    // one timestep of h, in elements
#define RING 4                  // h0/h1 ring slots (reuse dist 4 >> read dist 1)

typedef __attribute__((ext_vector_type(8))) short bf16x8;
typedef __attribute__((ext_vector_type(4))) float f32x4;
typedef unsigned int uint;
typedef unsigned short ushort;

// ---- helpers -------------------------------------------------------------

// swizzled element index into a [rows][512] bf16 LDS tile (row stride 1024B).
// XOR of (row&7)<<3 elements == (row&7)<<4 bytes: spreads the stride-1024B
// column accesses across 8 distinct 16B slots -> 2-way bank aliasing (free).
__device__ __forceinline__ int swzE(int row, int k) {
    return row * 512 + (k ^ ((row & 7) << 3));
}

__device__ __forceinline__ ushort f2bf(float f) {  // RNE float->bf16
    uint u = __builtin_bit_cast(uint, f);
    u = (u + 0x7FFFu + ((u >> 16) & 1u)) >> 16;
    return (ushort)u;
}

__device__ __forceinline__ float sigm(float x) {
    x = fminf(fmaxf(x, -30.f), 30.f);
    return 1.f / (1.f + __expf(-x));
}

__device__ __forceinline__ float tanh_(float x) {
    x = fminf(fmaxf(x, -15.f), 15.f);
    float e = __expf(2.f * x);
    return (e - 1.f) / (e + 1.f);
}

// stage one timestep of h (64 rows x 512 cols bf16 = 64KB) global -> swizzled
// LDS. 4096 chunks of 8 elems (16B); 64 chunks per row.
__device__ __forceinline__ void stage64(const ushort* __restrict__ src,
                                        ushort* stg, int tid) {
    #pragma unroll
    for (int i = 0; i < 16; ++i) {
        int c = tid + THREADS * i;       // 0..4095
        int row = c >> 6;                // 64 chunks/row -> rows 0..63
        int kE = (c & 63) << 3;          // k element 0..504
        uint4 v = *(const uint4*)(src + row * 512 + kE);
        *(uint4*)(stg + swzE(row, kE)) = v;
    }
}

// load a 32-col weight slice [32][512] f32 -> bf16 swizzled LDS.
// col n (0..31): gate (n>>3), h-local (n&7) => global gate col.
__device__ __forceinline__ void loadW(const float* __restrict__ g, ushort* W,
                                      int wg, int tid) {
    #pragma unroll
    for (int i = 0; i < 8; ++i) {
        int c = tid + THREADS * i;       // 2048 chunks of 8 elems
        int n = c >> 6;
        int kE = (c & 63) << 3;
        int gcol = ((n >> 3) << 9) + (wg << 3) + (n & 7);
        const float* s = g + (size_t)gcol * 512 + kE;
        float4 f0 = *(const float4*)s;
        float4 f1 = *(const float4*)(s + 4);
        uint4 v;
        v.x = (uint)f2bf(f0.x) | ((uint)f2bf(f0.y) << 16);
        v.y = (uint)f2bf(f0.z) | ((uint)f2bf(f0.w) << 16);
        v.z = (uint)f2bf(f1.x) | ((uint)f2bf(f1.y) << 16);
        v.w = (uint)f2bf(f1.z) | ((uint)f2bf(f1.w) << 16);
        *(uint4*)(W + swzE(n, kE)) = v;
    }
}

// 64x32 += 64x512 @ (512x32) over staged A and weight slice W
__device__ __forceinline__ void gemm_acc(const ushort* stg, const ushort* W,
                                         int l, int wv, f32x4& acc0, f32x4& acc1) {
    const int arow = (wv << 4) + (l & 15);
    const int koff = (l >> 4) << 3;
    #pragma unroll
    for (int ks = 0; ks < 16; ++ks) {
        int k = (ks << 5) + koff;
        bf16x8 a  = *(const bf16x8*)(stg + swzE(arow, k));
        bf16x8 b0 = *(const bf16x8*)(W + swzE((l & 15), k));
        bf16x8 b1 = *(const bf16x8*)(W + swzE(16 + (l & 15), k));
        acc0 = __builtin_amdgcn_mfma_f32_16x16x32_bf16(a, b0, acc0, 0, 0, 0);
        acc1 = __builtin_amdgcn_mfma_f32_16x16x32_bf16(a, b1, acc1, 0, 0, 0);
    }
}

// ---- persistent 3-layer pipelined scan ----------------------------------

__global__ __launch_bounds__(THREADS, 1)
void lstm_scan(const float* __restrict__ feat,
               const float* __restrict__ wih0, const float* __restrict__ whh0,
               const float* __restrict__ bih0, const float* __restrict__ bhh0,
               const float* __restrict__ wih1, const float* __restrict__ whh1,
               const float* __restrict__ bih1, const float* __restrict__ bhh1,
               const float* __restrict__ wih2, const float* __restrict__ whh2,
               const float* __restrict__ bih2, const float* __restrict__ bhh2,
               ushort* h0buf, ushort* h1buf, ushort* h2ring, ushort* ybuf,
               uint* bar) {
    extern __shared__ char smem[];
    ushort* Wih   = (ushort*)smem;            // [32][512] bf16 (L>=1)
    ushort* Whh   = Wih + 32 * 512;           // [32][512] bf16
    ushort* stg   = Whh + 32 * 512;           // [64][512] bf16 staging
    float*  gates = (float*)(stg + 64 * 512); // [64][33] f32 (padded)
    float*  cst   = gates + 64 * 33;          // [64][8] f32 cell state
    float*  biasl = cst + 64 * 8;             // [32]
    float*  w0l   = biasl + 32;               // [32][6] f32 (L0 input proj)

    const int blk = blockIdx.x;
    const int L   = blk / NGROUP;
    const int wg  = blk % NGROUP;
    const int tid = threadIdx.x;
    const int wv  = tid >> 6;
    const int l   = tid & 63;

    const float* wih_g = (L == 0) ? wih0 : (L == 1) ? wih1 : wih2;
    const float* whh_g = (L == 0) ? whh0 : (L == 1) ? whh1 : whh2;
    const float* bih_g = (L == 0) ? bih0 : (L == 1) ? bih1 : bih2;
    const float* bhh_g = (L == 0) ? bhh0 : (L == 1) ? bhh1 : bhh2;
    const ushort* xsrc = (L == 1) ? h0buf : (L == 2) ? h1buf : nullptr;
    ushort* hout = (L == 0) ? h0buf : (L == 1) ? h1buf : nullptr; // L2 uses ring

    // ---- one-time preload ----
    loadW(whh_g, Whh, wg, tid);
    if (L > 0) loadW(wih_g, Wih, wg, tid);
    if (L == 0 && tid < 192) {
        int n = tid / 6, d = tid - n * 6;
        int gcol = ((n >> 3) << 9) + (wg << 3) + (n & 7);
        w0l[n * 6 + d] = wih0[gcol * 6 + d];
    }
    if (tid < 32) {
        int gcol = ((tid >> 3) << 9) + (wg << 3) + (tid & 7);
        biasl[tid] = bih_g[gcol] + bhh_g[gcol];
    }
    for (int i = tid; i < 64 * 8; i += THREADS) cst[i] = 0.f;
    __syncthreads();

    for (int s = 0; s < S_TOTAL; ++s) {
        const int t = s - L;
        if (t >= 0 && t < T_STEPS) {
            f32x4 acc0 = {0.f, 0.f, 0.f, 0.f};
            f32x4 acc1 = {0.f, 0.f, 0.f, 0.f};

            if (L > 0) {  // input projection: x = h_{L-1}[t]
                stage64(xsrc + (size_t)(t & (RING - 1)) * HSLICE, stg, tid);
                __syncthreads();
                gemm_acc(stg, Wih, l, wv, acc0, acc1);
                __syncthreads();  // done reading stg before re-stage
            }
            if (t > 0) {  // recurrent: h_L[t-1]
                const ushort* src = (L == 2)
                    ? (h2ring + (size_t)((t - 1) & 1) * HSLICE)
                    : (hout + (size_t)((t - 1) & (RING - 1)) * HSLICE);
                stage64(src, stg, tid);
                __syncthreads();
                gemm_acc(stg, Whh, l, wv, acc0, acc1);
            }

            // scatter accumulators to LDS: D row=(l>>4)*4+r (batch), col=l&15
            {
                int r0 = (wv << 4) + ((l >> 4) << 2);
                int cc = l & 15;
                #pragma unroll
                for (int r = 0; r < 4; ++r) {
                    gates[(r0 + r) * 33 + cc]      = acc0[r];
                    gates[(r0 + r) * 33 + 16 + cc] = acc1[r];
                }
            }
            __syncthreads();

            // activations: each thread owns 2 (b, j) pairs
            {
                int p  = tid << 1;
                int b  = p >> 3;
                int jl = p & 7;       // even; handles jl, jl+1 (same b)
                float xv[6];
                if (L == 0) {
                    #pragma unroll
                    for (int d = 0; d < 6; ++d)
                        xv[d] = feat[(size_t)(b * 6 + d) * T_STEPS + t];
                }
                uint pack = 0;
                #pragma unroll
                for (int q = 0; q < 2; ++q) {
                    int n = jl + q;
                    float i_ = gates[b * 33 + n]      + biasl[n];
                    float f_ = gates[b * 33 + 8 + n]  + biasl[8 + n];
                    float g_ = gates[b * 33 + 16 + n] + biasl[16 + n];
                    float o_ = gates[b * 33 + 24 + n] + biasl[24 + n];
                    if (L == 0) {
                        #pragma unroll
                        for (int d = 0; d < 6; ++d) {
                            float x = xv[d];
                            i_ += w0l[n * 6 + d] * x;
                            f_ += w0l[(8 + n) * 6 + d] * x;
                            g_ += w0l[(16 + n) * 6 + d] * x;
                            o_ += w0l[(24 + n) * 6 + d] * x;
                        }
                    }
                    float ii = sigm(i_), ff = sigm(f_);
                    float gg = tanh_(g_), oo = sigm(o_);
                    float c = ff * cst[b * 8 + n] + ii * gg;
                    cst[b * 8 + n] = c;
                    float h = oo * tanh_(c);
                    pack |= ((uint)f2bf(h)) << (16 * q);
                }
                int j = (wg << 3) + jl;
                if (L == 2) {
                    *(uint*)&h2ring[(size_t)(t & 1) * HSLICE + b * 512 + j] = pack;
                    if ((t & 7) == 7)
                        *(uint*)&ybuf[(size_t)(t >> 3) * HSLICE + b * 512 + j] = pack;
                } else {
                    *(uint*)&hout[(size_t)(t & (RING - 1)) * HSLICE + b * 512 + j] = pack;
                }
            }
        }

        // grid barrier (all NWG arrive every step). Ordering is carried by
        // the barrier atomics themselves: RELEASE on the increment publishes
        // this block's h-stores at agent scope; ACQUIRE on the spin load
        // makes all other blocks' published stores visible here.
        if (s < S_TOTAL - 1) {
            __syncthreads();
            if (tid == 0) {
                __hip_atomic_fetch_add(bar, 1u, __ATOMIC_RELEASE, __HIP_MEMORY_SCOPE_AGENT);
                const uint tgt = (uint)NWG * (uint)(s + 1);
                while (__hip_atomic_load(bar, __ATOMIC_ACQUIRE, __HIP_MEMORY_SCOPE_AGENT) < tgt) {}
            }
            __syncthreads();
        }
    }
}

// ---- final projection: out[8192][256] = y[8192][512] @ w_out^T + b_out ---

__global__ __launch_bounds__(256, 1)
void out_gemm(const ushort* __restrict__ y, const float* __restrict__ wout,
              const float* __restrict__ bout, float* __restrict__ out) {
    __shared__ ushort Bl[64 * 512];  // 64 output cols x 512, bf16 swizzled
    const int bm = blockIdx.x;       // 128 m-tiles of 64 rows
    const int bn = blockIdx.y;       // 4 n-tiles of 64 cols
    const int tid = threadIdx.x, wv = tid >> 6, l = tid & 63;

    #pragma unroll
    for (int i = 0; i < 16; ++i) {
        int c = tid + 256 * i;
        int n = c >> 6;
        int kE = (c & 63) << 3;
        const float* s = wout + (size_t)(bn * 64 + n) * 512 + kE;
        float4 f0 = *(const float4*)s;
        float4 f1 = *(const float4*)(s + 4);
        uint4 v;
        v.x = (uint)f2bf(f0.x) | ((uint)f2bf(f0.y) << 16);
        v.y = (uint)f2bf(f0.z) | ((uint)f2bf(f0.w) << 16);
        v.z = (uint)f2bf(f1.x) | ((uint)f2bf(f1.y) << 16);
        v.w = (uint)f2bf(f1.z) | ((uint)f2bf(f1.w) << 16);
        *(uint4*)(Bl + swzE(n, kE)) = v;
    }
    __syncthreads();

    const int m0 = bm * 64 + (wv << 4);
    const int arow = m0 + (l & 15);
    const int koff = (l >> 4) << 3;
    f32x4 acc[4] = {{0.f,0.f,0.f,0.f},{0.f,0.f,0.f,0.f},{0.f,0.f,0.f,0.f},{0.f,0.f,0.f,0.f}};
    for (int ks = 0; ks < 16; ++ks) {
        int k = (ks << 5) + koff;
        bf16x8 a = *(const bf16x8*)(y + (size_t)arow * 512 + k);
        #pragma unroll
        for (int nt = 0; nt < 4; ++nt) {
            bf16x8 b = *(const bf16x8*)(Bl + swzE((nt << 4) + (l & 15), k));
            acc[nt] = __builtin_amdgcn_mfma_f32_16x16x32_bf16(a, b, acc[nt], 0, 0, 0);
        }
    }
    const int r0 = (l >> 4) << 2;
    #pragma unroll
    for (int nt = 0; nt < 4; ++nt) {
        int n = bn * 64 + (nt << 4) + (l & 15);
        float bo = bout[n];
        #pragma unroll
        for (int r = 0; r < 4; ++r) {
            int m = m0 + r0 + r;
            out[(size_t)m * 256 + n] = acc[nt][r] + bo;
        }
    }
}

// ---- launch --------------------------------------------------------------

#define SCAN_LDS ((32*512 + 32*512 + 64*512) * 2 + (64*33 + 64*8 + 32 + 32*6) * 4)

extern "C" void kernel_launch(void* const* d_in, const int* in_sizes, int n_in,
                              void* d_out, int out_size, void* d_ws, size_t ws_size,
                              hipStream_t stream) {
    const float* feat = (const float*)d_in[0];
    const float* wih0 = (const float*)d_in[1];
    const float* whh0 = (const float*)d_in[2];
    const float* bih0 = (const float*)d_in[3];
    const float* bhh0 = (const float*)d_in[4];
    const float* wih1 = (const float*)d_in[5];
    const float* whh1 = (const float*)d_in[6];
    const float* bih1 = (const float*)d_in[7];
    const float* bhh1 = (const float*)d_in[8];
    const float* wih2 = (const float*)d_in[9];
    const float* whh2 = (const float*)d_in[10];
    const float* bih2 = (const float*)d_in[11];
    const float* bhh2 = (const float*)d_in[12];
    const float* wout = (const float*)d_in[13];
    const float* bout = (const float*)d_in[14];

    char* ws = (char*)d_ws;
    uint*   bar   = (uint*)ws;
    ushort* h0    = (ushort*)(ws + 4096);                  // RING x 64KB
    ushort* h1    = h0 + (size_t)RING * HSLICE;            // RING x 64KB
    ushort* h2r   = h1 + (size_t)RING * HSLICE;            // 2 x 64KB
    ushort* ybuf  = h2r + (size_t)2 * HSLICE;              // 128 x 64KB = 8MB
    float*  out   = (float*)d_out;

    (void)hipMemsetAsync(bar, 0, 256, stream);

    (void)hipFuncSetAttribute((const void*)lstm_scan,
                              hipFuncAttributeMaxDynamicSharedMemorySize, SCAN_LDS);

    hipLaunchKernelGGL(lstm_scan, dim3(NWG), dim3(THREADS), SCAN_LDS, stream,
                       feat, wih0, whh0, bih0, bhh0, wih1, whh1, bih1, bhh1,
                       wih2, whh2, bih2, bhh2, h0, h1, h2r, ybuf, bar);

    hipLaunchKernelGGL(out_gemm, dim3(128, 4), dim3(256), 0, stream,
                       ybuf, wout, bout, out);
}

// Round 4
// 11447.943 us; speedup vs baseline: 1.9689x; 1.9689x over previous
//
#include <hip/hip_runtime.h>
#include <stdint.h>

#define T_STEPS 1024
#define BATCH 64
#define HID 512
#define NGROUP 64               // workgroups per layer
#define NLAYER 3
#define NWG (NGROUP * NLAYER)   // 192
#define THREADS 256
#define S_TOTAL (T_STEPS + NLAYER - 1)  // 1026 global steps
#define HSLICE (BATCH * HID)    // one timestep of h, in elements
#define RING 4                  // h0/h1 ring slots

typedef __attribute__((ext_vector_type(8))) short bf16x8;
typedef __attribute__((ext_vector_type(4))) float f32x4;
typedef unsigned int uint;
typedef unsigned short ushort;

// ---- helpers -------------------------------------------------------------

// swizzle used only by out_gemm's B tile ([rows][512] bf16)
__device__ __forceinline__ int swzE(int row, int k) {
    return row * 512 + (k ^ ((row & 7) << 3));
}

__device__ __forceinline__ ushort f2bf(float f) {  // RNE float->bf16
    uint u = __builtin_bit_cast(uint, f);
    u = (u + 0x7FFFu + ((u >> 16) & 1u)) >> 16;
    return (ushort)u;
}

__device__ __forceinline__ float sigm(float x) {
    x = fminf(fmaxf(x, -30.f), 30.f);
    return 1.f / (1.f + __expf(-x));
}

__device__ __forceinline__ float tanh_(float x) {
    x = fminf(fmaxf(x, -15.f), 15.f);
    float e = __expf(2.f * x);
    return (e - 1.f) / (e + 1.f);
}

// load a 32-col weight slice (4H x K f32) into FRAGMENT-ORDERED bf16 LDS:
// dest element ((ks*2+half)*64 + q*16 + r)*8 + e  holds W[col = half*16+r
// (local)][k = ks*32+q*8+e].  GEMM reads are then lane-contiguous 16B ->
// conflict-free.  (The scattered writes here are 64-way conflicted but run
// once at startup.)
__device__ __forceinline__ void loadW(const float* __restrict__ g, ushort* W,
                                      int wg, int tid) {
    #pragma unroll
    for (int i = 0; i < 8; ++i) {
        int c = tid + THREADS * i;       // 2048 chunks of 8 elems
        int n = c >> 6;                  // local col 0..31
        int kE = (c & 63) << 3;          // k 0..504 step 8
        int ks = kE >> 5, q = (kE >> 3) & 3, half = n >> 4, r = n & 15;
        int gcol = ((n >> 3) << 9) + (wg << 3) + (n & 7);
        const float* s = g + (size_t)gcol * 512 + kE;
        float4 f0 = *(const float4*)s;
        float4 f1 = *(const float4*)(s + 4);
        uint4 v;
        v.x = (uint)f2bf(f0.x) | ((uint)f2bf(f0.y) << 16);
        v.y = (uint)f2bf(f0.z) | ((uint)f2bf(f0.w) << 16);
        v.z = (uint)f2bf(f1.x) | ((uint)f2bf(f1.y) << 16);
        v.w = (uint)f2bf(f1.z) | ((uint)f2bf(f1.w) << 16);
        *(uint4*)(W + (size_t)(((ks * 2 + half) * 64 + q * 16 + r) * 8)) = v;
    }
}

// 64x32 += A(64x512 row-major, global) @ Wf(512x32, fragment LDS)
__device__ __forceinline__ void gemm1(const ushort* __restrict__ A,
                                      const ushort* Bf, int l, int wv,
                                      f32x4& acc0, f32x4& acc1) {
    const ushort* ap = A + ((wv << 4) + (l & 15)) * 512 + ((l >> 4) << 3);
    #pragma unroll
    for (int ks = 0; ks < 16; ++ks) {
        bf16x8 a  = *(const bf16x8*)(ap + ks * 32);
        bf16x8 b0 = *(const bf16x8*)(Bf + ((ks * 2 + 0) * 64 + l) * 8);
        bf16x8 b1 = *(const bf16x8*)(Bf + ((ks * 2 + 1) * 64 + l) * 8);
        acc0 = __builtin_amdgcn_mfma_f32_16x16x32_bf16(a, b0, acc0, 0, 0, 0);
        acc1 = __builtin_amdgcn_mfma_f32_16x16x32_bf16(a, b1, acc1, 0, 0, 0);
    }
}

// combined: acc += Ax @ BfX + Ah @ BfH (overlaps the two load streams)
__device__ __forceinline__ void gemm2(const ushort* __restrict__ Ax,
                                      const ushort* BfX,
                                      const ushort* __restrict__ Ah,
                                      const ushort* BfH, int l, int wv,
                                      f32x4& acc0, f32x4& acc1) {
    const int ro = ((wv << 4) + (l & 15)) * 512 + ((l >> 4) << 3);
    const ushort* axp = Ax + ro;
    const ushort* ahp = Ah + ro;
    #pragma unroll
    for (int ks = 0; ks < 16; ++ks) {
        bf16x8 ax = *(const bf16x8*)(axp + ks * 32);
        bf16x8 ah = *(const bf16x8*)(ahp + ks * 32);
        bf16x8 x0 = *(const bf16x8*)(BfX + ((ks * 2 + 0) * 64 + l) * 8);
        bf16x8 x1 = *(const bf16x8*)(BfX + ((ks * 2 + 1) * 64 + l) * 8);
        bf16x8 h0 = *(const bf16x8*)(BfH + ((ks * 2 + 0) * 64 + l) * 8);
        bf16x8 h1 = *(const bf16x8*)(BfH + ((ks * 2 + 1) * 64 + l) * 8);
        acc0 = __builtin_amdgcn_mfma_f32_16x16x32_bf16(ax, x0, acc0, 0, 0, 0);
        acc1 = __builtin_amdgcn_mfma_f32_16x16x32_bf16(ax, x1, acc1, 0, 0, 0);
        acc0 = __builtin_amdgcn_mfma_f32_16x16x32_bf16(ah, h0, acc0, 0, 0, 0);
        acc1 = __builtin_amdgcn_mfma_f32_16x16x32_bf16(ah, h1, acc1, 0, 0, 0);
    }
}

// ---- persistent 3-layer pipelined scan ----------------------------------

__global__ __launch_bounds__(THREADS, 1)
void lstm_scan(const float* __restrict__ feat,
               const float* __restrict__ wih0, const float* __restrict__ whh0,
               const float* __restrict__ bih0, const float* __restrict__ bhh0,
               const float* __restrict__ wih1, const float* __restrict__ whh1,
               const float* __restrict__ bih1, const float* __restrict__ bhh1,
               const float* __restrict__ wih2, const float* __restrict__ whh2,
               const float* __restrict__ bih2, const float* __restrict__ bhh2,
               ushort* h0buf, ushort* h1buf, ushort* h2ring, ushort* ybuf,
               uint* bar) {
    extern __shared__ char smem[];
    ushort* Wihf  = (ushort*)smem;            // [16][2][64][8] bf16 fragments
    ushort* Whhf  = Wihf + 16384;
    float*  gates = (float*)(Whhf + 16384);   // [64][33] f32 (padded)
    float*  cst   = gates + 64 * 33;          // [64][8] f32 cell state
    float*  biasl = cst + 64 * 8;             // [32]
    float*  w0l   = biasl + 32;               // [32][6] f32 (L0 input proj)

    const int blk = blockIdx.x;
    const int L   = blk / NGROUP;
    const int wg  = blk % NGROUP;
    const int tid = threadIdx.x;
    const int wv  = tid >> 6;
    const int l   = tid & 63;

    const float* wih_g = (L == 0) ? wih0 : (L == 1) ? wih1 : wih2;
    const float* whh_g = (L == 0) ? whh0 : (L == 1) ? whh1 : whh2;
    const float* bih_g = (L == 0) ? bih0 : (L == 1) ? bih1 : bih2;
    const float* bhh_g = (L == 0) ? bhh0 : (L == 1) ? bhh1 : bhh2;
    const ushort* xsrc = (L == 1) ? h0buf : (L == 2) ? h1buf : nullptr;
    ushort* hout = (L == 0) ? h0buf : (L == 1) ? h1buf : nullptr; // L2: ring

    // ---- one-time preload ----
    loadW(whh_g, Whhf, wg, tid);
    if (L > 0) loadW(wih_g, Wihf, wg, tid);
    if (L == 0 && tid < 192) {
        int n = tid / 6, d = tid - n * 6;
        int gcol = ((n >> 3) << 9) + (wg << 3) + (n & 7);
        w0l[n * 6 + d] = wih0[gcol * 6 + d];
    }
    if (tid < 32) {
        int gcol = ((tid >> 3) << 9) + (wg << 3) + (tid & 7);
        biasl[tid] = bih_g[gcol] + bhh_g[gcol];
    }
    for (int i = tid; i < 64 * 8; i += THREADS) cst[i] = 0.f;
    __syncthreads();

    uint* cnt   = bar;        // arrival counter (own cacheline)
    uint* epoch = bar + 64;   // broadcast word  (separate cacheline)

    for (int s = 0; s < S_TOTAL; ++s) {
        const int t = s - L;
        if (t >= 0 && t < T_STEPS) {
            f32x4 acc0 = {0.f, 0.f, 0.f, 0.f};
            f32x4 acc1 = {0.f, 0.f, 0.f, 0.f};

            if (L > 0) {
                const ushort* xs = xsrc + (size_t)(t & (RING - 1)) * HSLICE;
                if (t > 0) {
                    const ushort* hs = (L == 2)
                        ? (h2ring + (size_t)((t - 1) & 1) * HSLICE)
                        : (hout + (size_t)((t - 1) & (RING - 1)) * HSLICE);
                    gemm2(xs, Wihf, hs, Whhf, l, wv, acc0, acc1);
                } else {
                    gemm1(xs, Wihf, l, wv, acc0, acc1);
                }
            } else if (t > 0) {
                const ushort* hs = hout + (size_t)((t - 1) & (RING - 1)) * HSLICE;
                gemm1(hs, Whhf, l, wv, acc0, acc1);
            }

            // scatter accumulators to LDS: row=(wv*16 + (l>>4)*4 + r), col=l&15
            {
                int r0 = (wv << 4) + ((l >> 4) << 2);
                int cc = l & 15;
                #pragma unroll
                for (int r = 0; r < 4; ++r) {
                    gates[(r0 + r) * 33 + cc]      = acc0[r];
                    gates[(r0 + r) * 33 + 16 + cc] = acc1[r];
                }
            }
            __syncthreads();

            // activations: each thread owns 2 (b, j) pairs
            {
                int p  = tid << 1;
                int b  = p >> 3;
                int jl = p & 7;       // even; handles jl, jl+1 (same b)
                float xv[6];
                if (L == 0) {
                    #pragma unroll
                    for (int d = 0; d < 6; ++d)
                        xv[d] = feat[(size_t)(b * 6 + d) * T_STEPS + t];
                }
                uint pack = 0;
                #pragma unroll
                for (int q = 0; q < 2; ++q) {
                    int n = jl + q;
                    float i_ = gates[b * 33 + n]      + biasl[n];
                    float f_ = gates[b * 33 + 8 + n]  + biasl[8 + n];
                    float g_ = gates[b * 33 + 16 + n] + biasl[16 + n];
                    float o_ = gates[b * 33 + 24 + n] + biasl[24 + n];
                    if (L == 0) {
                        #pragma unroll
                        for (int d = 0; d < 6; ++d) {
                            float x = xv[d];
                            i_ += w0l[n * 6 + d] * x;
                            f_ += w0l[(8 + n) * 6 + d] * x;
                            g_ += w0l[(16 + n) * 6 + d] * x;
                            o_ += w0l[(24 + n) * 6 + d] * x;
                        }
                    }
                    float ii = sigm(i_), ff = sigm(f_);
                    float gg = tanh_(g_), oo = sigm(o_);
                    float c = ff * cst[b * 8 + n] + ii * gg;
                    cst[b * 8 + n] = c;
                    float h = oo * tanh_(c);
                    pack |= ((uint)f2bf(h)) << (16 * q);
                }
                int j = (wg << 3) + jl;
                if (L == 2) {
                    *(uint*)&h2ring[(size_t)(t & 1) * HSLICE + b * 512 + j] = pack;
                    if ((t & 7) == 7)
                        *(uint*)&ybuf[(size_t)(t >> 3) * HSLICE + b * 512 + j] = pack;
                } else {
                    *(uint*)&hout[(size_t)(t & (RING - 1)) * HSLICE + b * 512 + j] = pack;
                }
            }
        }

        // grid barrier, epoch-broadcast style:
        //  - one RELEASE fetch_add per block (publishes h; small dirty set)
        //  - last arriver stores epoch; everyone else polls RELAXED + s_sleep
        //  - exactly ONE ACQUIRE load per block per step (one invalidate)
        if (s < S_TOTAL - 1) {
            __syncthreads();
            if (tid == 0) {
                uint old = __hip_atomic_fetch_add(cnt, 1u, __ATOMIC_RELEASE,
                                                  __HIP_MEMORY_SCOPE_AGENT);
                const uint tgt = (uint)NWG * (uint)(s + 1);
                if (old == tgt - 1) {
                    __hip_atomic_store(epoch, (uint)(s + 1), __ATOMIC_RELEASE,
                                       __HIP_MEMORY_SCOPE_AGENT);
                } else {
                    while (__hip_atomic_load(epoch, __ATOMIC_RELAXED,
                                             __HIP_MEMORY_SCOPE_AGENT) < (uint)(s + 1))
                        __builtin_amdgcn_s_sleep(4);
                }
                (void)__hip_atomic_load(epoch, __ATOMIC_ACQUIRE,
                                        __HIP_MEMORY_SCOPE_AGENT);
            }
            __syncthreads();
        }
    }
}

// ---- final projection: out[8192][256] = y[8192][512] @ w_out^T + b_out ---

__global__ __launch_bounds__(256, 1)
void out_gemm(const ushort* __restrict__ y, const float* __restrict__ wout,
              const float* __restrict__ bout, float* __restrict__ out) {
    __shared__ ushort Bl[64 * 512];  // 64 output cols x 512, bf16 swizzled
    const int bm = blockIdx.x;       // 128 m-tiles of 64 rows
    const int bn = blockIdx.y;       // 4 n-tiles of 64 cols
    const int tid = threadIdx.x, wv = tid >> 6, l = tid & 63;

    #pragma unroll
    for (int i = 0; i < 16; ++i) {
        int c = tid + 256 * i;
        int n = c >> 6;
        int kE = (c & 63) << 3;
        const float* s = wout + (size_t)(bn * 64 + n) * 512 + kE;
        float4 f0 = *(const float4*)s;
        float4 f1 = *(const float4*)(s + 4);
        uint4 v;
        v.x = (uint)f2bf(f0.x) | ((uint)f2bf(f0.y) << 16);
        v.y = (uint)f2bf(f0.z) | ((uint)f2bf(f0.w) << 16);
        v.z = (uint)f2bf(f1.x) | ((uint)f2bf(f1.y) << 16);
        v.w = (uint)f2bf(f1.z) | ((uint)f2bf(f1.w) << 16);
        *(uint4*)(Bl + swzE(n, kE)) = v;
    }
    __syncthreads();

    const int m0 = bm * 64 + (wv << 4);
    const int arow = m0 + (l & 15);
    const int koff = (l >> 4) << 3;
    f32x4 acc[4] = {{0.f,0.f,0.f,0.f},{0.f,0.f,0.f,0.f},{0.f,0.f,0.f,0.f},{0.f,0.f,0.f,0.f}};
    for (int ks = 0; ks < 16; ++ks) {
        int k = (ks << 5) + koff;
        bf16x8 a = *(const bf16x8*)(y + (size_t)arow * 512 + k);
        #pragma unroll
        for (int nt = 0; nt < 4; ++nt) {
            bf16x8 b = *(const bf16x8*)(Bl + swzE((nt << 4) + (l & 15), k));
            acc[nt] = __builtin_amdgcn_mfma_f32_16x16x32_bf16(a, b, acc[nt], 0, 0, 0);
        }
    }
    const int r0 = (l >> 4) << 2;
    #pragma unroll
    for (int nt = 0; nt < 4; ++nt) {
        int n = bn * 64 + (nt << 4) + (l & 15);
        float bo = bout[n];
        #pragma unroll
        for (int r = 0; r < 4; ++r) {
            int m = m0 + r0 + r;
            out[(size_t)m * 256 + n] = acc[nt][r] + bo;
        }
    }
}

// ---- launch --------------------------------------------------------------

#define SCAN_LDS (16384*2*2 + (64*33 + 64*8 + 32 + 32*6) * 4)

extern "C" void kernel_launch(void* const* d_in, const int* in_sizes, int n_in,
                              void* d_out, int out_size, void* d_ws, size_t ws_size,
                              hipStream_t stream) {
    const float* feat = (const float*)d_in[0];
    const float* wih0 = (const float*)d_in[1];
    const float* whh0 = (const float*)d_in[2];
    const float* bih0 = (const float*)d_in[3];
    const float* bhh0 = (const float*)d_in[4];
    const float* wih1 = (const float*)d_in[5];
    const float* whh1 = (const float*)d_in[6];
    const float* bih1 = (const float*)d_in[7];
    const float* bhh1 = (const float*)d_in[8];
    const float* wih2 = (const float*)d_in[9];
    const float* whh2 = (const float*)d_in[10];
    const float* bih2 = (const float*)d_in[11];
    const float* bhh2 = (const float*)d_in[12];
    const float* wout = (const float*)d_in[13];
    const float* bout = (const float*)d_in[14];

    char* ws = (char*)d_ws;
    uint*   bar   = (uint*)ws;
    ushort* h0    = (ushort*)(ws + 4096);                  // RING x 64KB
    ushort* h1    = h0 + (size_t)RING * HSLICE;            // RING x 64KB
    ushort* h2r   = h1 + (size_t)RING * HSLICE;            // 2 x 64KB
    ushort* ybuf  = h2r + (size_t)2 * HSLICE;              // 128 x 64KB = 8MB
    float*  out   = (float*)d_out;

    (void)hipMemsetAsync(bar, 0, 4096, stream);

    (void)hipFuncSetAttribute((const void*)lstm_scan,
                              hipFuncAttributeMaxDynamicSharedMemorySize, SCAN_LDS);

    hipLaunchKernelGGL(lstm_scan, dim3(NWG), dim3(THREADS), SCAN_LDS, stream,
                       feat, wih0, whh0, bih0, bhh0, wih1, whh1, bih1, bhh1,
                       wih2, whh2, bih2, bhh2, h0, h1, h2r, ybuf, bar);

    hipLaunchKernelGGL(out_gemm, dim3(128, 4), dim3(256), 0, stream,
                       ybuf, wout, bout, out);
}